// Round 13
// baseline (407.254 us; speedup 1.0000x reference)
//
#include <hip/hip_runtime.h>
#include <hip/hip_bf16.h>

// Inputs f32 (proven R1/R4). Output f32.

#define N_NODES 4096
#define N_EDGES 16384
#define N_GRAPHS 16
#define HD 128   // hidden dim
#define BM 128   // edges per block in MFMA gemm
#define LDB 136  // padded LDS row stride in w2t_prep only
#define KSPLIT 4              // k-slab splits, XCD-uniform (ks = bid&3)
#define KT_PER (HD / KSPLIT)  // 32 slabs per split
#define SLAB_E (HD * HD)      // ushorts per B slab (32 KB)
#define PN 32                 // nodes per pool_scatter block

typedef unsigned short ushort_t;
typedef __attribute__((ext_vector_type(8))) short short8;  // 8 bf16 = 4 VGPR (MFMA A/B frag)
typedef __attribute__((ext_vector_type(4))) float f32x4;   // MFMA C/D frag

static __device__ __forceinline__ ushort_t f2b(float f) {
    __hip_bfloat16 h = __float2bfloat16(f);
    union { __hip_bfloat16 h; ushort_t u; } cv; cv.h = h; return cv.u;
}
static __device__ __forceinline__ float b2f(ushort_t u) {
    union { unsigned u; float f; } cv; cv.u = ((unsigned)u) << 16; return cv.f;
}

static __device__ __forceinline__ float wave_sum(float v) {
#pragma unroll
    for (int off = 1; off < 64; off <<= 1) v += __shfl_xor(v, off, 64);
    return v;
}

// ---- count incoming edges per node -------------------------------------
__global__ __launch_bounds__(256) void count_k(const int* __restrict__ dst, float* __restrict__ cnt) {
    int e = blockIdx.x * 256 + threadIdx.x;
    atomicAdd(&cnt[dst[e]], 1.0f);
}

// ---- layer 1 edge kernel (in_c = 3), f32 VALU (tiny) -------------------
__global__ __launch_bounds__(128) void l1_edge(
    const float* __restrict__ x, const int* __restrict__ src, const int* __restrict__ dst,
    const float* __restrict__ ea, const float* __restrict__ w1, const float* __restrict__ b1,
    const float* __restrict__ w2, const float* __restrict__ b2, float* __restrict__ agg) {
    __shared__ float h[4][HD];
    __shared__ float xsrc[4][3];
    const int o = threadIdx.x;
    const int e0 = blockIdx.x * 4;
#pragma unroll
    for (int q = 0; q < 4; ++q) {
        float s = b1[o];
#pragma unroll
        for (int j = 0; j < 4; ++j) s = fmaf(ea[(e0 + q) * 4 + j], w1[j * HD + o], s);
        h[q][o] = fmaxf(s, 0.0f);
    }
    if (o < 12) { int q = o / 3, i = o % 3; xsrc[q][i] = x[src[e0 + q] * 3 + i]; }
    __syncthreads();
    float acc[4] = {0.f, 0.f, 0.f, 0.f};
    for (int i = 0; i < 3; ++i) {
        float bb = b2[i * HD + o];
        float w[4] = {bb, bb, bb, bb};
        for (int k = 0; k < HD; ++k) {
            float w2v = w2[k * 384 + i * HD + o];
#pragma unroll
            for (int q = 0; q < 4; ++q) w[q] = fmaf(h[q][k], w2v, w[q]);
        }
#pragma unroll
        for (int q = 0; q < 4; ++q) acc[q] = fmaf(xsrc[q][i], w[q], acc[q]);
    }
#pragma unroll
    for (int q = 0; q < 4; ++q) atomicAdd(&agg[dst[e0 + q] * HD + o], acc[q]);
}

// ---- layer-1 node update (IN PLACE): agg := relu(LN(agg/cnt + x@root + b))
__global__ __launch_bounds__(128) void node_update_l1(
    float* __restrict__ agg, const float* __restrict__ cnt, const float* __restrict__ x,
    const float* __restrict__ root, const float* __restrict__ bias,
    const float* __restrict__ lng, const float* __restrict__ lnb) {
    const int n = blockIdx.x, o = threadIdx.x;
    float s = bias[o];
#pragma unroll
    for (int i = 0; i < 3; ++i) s = fmaf(x[n * 3 + i], root[i * HD + o], s);
    float v = agg[n * HD + o] / fmaxf(cnt[n], 1.0f) + s;
    __shared__ float red[2];
    float ws = wave_sum(v);
    if ((o & 63) == 0) red[o >> 6] = ws;
    __syncthreads();
    float m = (red[0] + red[1]) * (1.0f / HD);
    float d = v - m;
    float ws2 = wave_sum(d * d);
    __syncthreads();
    if ((o & 63) == 0) red[o >> 6] = ws2;
    __syncthreads();
    float var = (red[0] + red[1]) * (1.0f / HD);
    float y = d * rsqrtf(var + 1e-5f) * lng[o] + lnb[o];
    agg[n * HD + o] = fmaxf(y, 0.0f);
}

// ---- one-time transpose+convert+FRAGMENT-ORDER pack --------------------
// w2t[kt] stored in per-wave consumption order:
// 16B chunk c = (ng*8 + ni*4 + kb)*64 + lane  holds
//   bf16(w2[kt][ k = kb*32 + (lane>>4)*8 .. +7 ][ o = ng*32 + ni*16 + (lane&15) ])
// so a wave's bf[ni][kb] load is ONE fully-coalesced 1KB global_load_dwordx4.
__global__ __launch_bounds__(256) void w2t_prep(const float* __restrict__ w2,
                                                const float* __restrict__ b2,
                                                ushort_t* __restrict__ w2t) {
    __shared__ ushort_t tile[HD][LDB];
    const int kt = blockIdx.x;  // 0..128
    const int t = threadIdx.x;
    const float* srcp = (kt < HD) ? (w2 + kt * HD * HD) : b2;
    for (int c = 0; c < 64; ++c) {
        int flat = c * 256 + t;          // 0..16383, coalesced over o
        int i = flat >> 7, o = flat & 127;
        tile[o][i] = f2b(srcp[i * HD + o]);
    }
    __syncthreads();
    uint4* outp = (uint4*)(w2t + (size_t)kt * SLAB_E);
    for (int it = 0; it < 8; ++it) {
        int c = it * 256 + t;            // output chunk 0..2047 (coalesced write)
        int ng = c >> 9, j = (c >> 6) & 7, l = c & 63;
        int ni = j >> 2, kb = j & 3;
        int R  = ng * 32 + ni * 16 + (l & 15);
        int ke = kb * 32 + (l >> 4) * 8;
        outp[c] = *(const uint4*)&tile[R][ke];
    }
}

// ---- heavy layers 2/3: MFMA GEMM, B straight from L1/L2 ---------------
// R13 = R12 with KSPLIT=4: grid 512 -> TWO blocks/CU (16 waves = 4
// waves/SIMD; 16x124 VGPR = 1984 <= 2048; 2x40KB LDS <= 160KB).
// Independent co-resident blocks overlap each other's L2 latency and
// barrier drains — the residual that intra-block scheduling (R5-R12,
// all ~86-96us) could not remove. ks = bid&3 stays XCD-uniform (XCD j
// sees only ks=j&3; per-XCD B slice 1.05MB << 4MB L2). R12's proven
// envelope kept: (512,2) bounds -> 124 VGPR, no spill; fragment-packed
// direct-B; reg ping-pong; per-slab phase-lock barrier.
__global__ __launch_bounds__(512, 2) void gemm_mfma(
    const float* __restrict__ hprev, const float* __restrict__ ea,
    const float* __restrict__ w1, const float* __restrict__ b1,
    const ushort_t* __restrict__ w2t,
    const int* __restrict__ src, const int* __restrict__ dst,
    float* __restrict__ agg) {
    __shared__ ushort_t Xs[SLAB_E];           // 32 KB gathered A (swizzled)
    __shared__ ushort_t HeT[KT_PER][BM];      // 8 KB edge-MLP outputs [s][e]

    const int t = threadIdx.x;
    const int lane = t & 63, quad = lane >> 4, l16 = lane & 15;
    const int wave = t >> 6;
    const int mg = wave >> 2;                 // M-group 0..1 (64 edges each)
    const int ng = wave & 3;                  // N-group 0..3 (32 cols each)
    const int eb = blockIdx.x >> 2;           // edge group 0..127
    const int ks = blockIdx.x & 3;            // k-split; XCD j sees ks = j&3 only
    const int k0 = ks * KT_PER;
    const int e0 = eb * BM;
    const int rbase = mg * 64;                // wave's edge-row base

    {   // stage gathered A (bf16, XOR-swizzled chunks) into Xs
        const int le = t >> 2;                // edge 0..127, 4 threads/edge
        const int j0 = (t & 3) * 4;           // first logical 16B chunk
        const int r7 = le & 7;
        const float* rp = hprev + src[e0 + le] * HD + (t & 3) * 32;
        ushort_t* xrow = Xs + le * HD;
#pragma unroll
        for (int c = 0; c < 4; ++c) {
            float4 va = ((const float4*)rp)[2 * c];
            float4 vb = ((const float4*)rp)[2 * c + 1];
            uint4 pk;
            pk.x = (unsigned)f2b(va.x) | ((unsigned)f2b(va.y) << 16);
            pk.y = (unsigned)f2b(va.z) | ((unsigned)f2b(va.w) << 16);
            pk.z = (unsigned)f2b(vb.x) | ((unsigned)f2b(vb.y) << 16);
            pk.w = (unsigned)f2b(vb.z) | ((unsigned)f2b(vb.w) << 16);
            *(uint4*)&xrow[((j0 + c) ^ r7) << 3] = pk;
        }
    }

    {   // edge MLP -> HeT[s][e] (bf16); attrs straight from global
        const int e = t & 127;
        const float4 av = ((const float4*)ea)[e0 + e];
        for (int kl = t >> 7; kl < KT_PER; kl += 4) {
            const int kt = k0 + kl;
            float s = b1[kt];
            s = fmaf(av.x, w1[0 * HD + kt], s);
            s = fmaf(av.y, w1[1 * HD + kt], s);
            s = fmaf(av.z, w1[2 * HD + kt], s);
            s = fmaf(av.w, w1[3 * HD + kt], s);
            HeT[kl][e] = f2b(fmaxf(s, 0.0f));
        }
    }
    __syncthreads();   // Xs + HeT visible; the only full barrier

    short8 afrag[4][4];  // A[m = rbase+mi*16+l16][k = kb*32+quad*8+j]
#pragma unroll
    for (int mi = 0; mi < 4; ++mi) {
        const int R = rbase + mi * 16 + l16;
        const ushort_t* rowp = Xs + R * HD;
        const int r7 = R & 7;
#pragma unroll
        for (int kb = 0; kb < 4; ++kb)
            afrag[mi][kb] = *(const short8*)&rowp[((kb * 4 + quad) ^ r7) << 3];
    }

    f32x4 acc[4][2];
#pragma unroll
    for (int mi = 0; mi < 4; ++mi)
#pragma unroll
        for (int ni = 0; ni < 2; ++ni)
            acc[mi][ni] = (f32x4){0.f, 0.f, 0.f, 0.f};

    // wave's per-slab fragment base: chunk (ng*8 + ni*4 + kb)*64 + lane
    const ushort_t* bbase = w2t + (size_t)ng * 4096 + (size_t)lane * 8;

#define LOADB(bf, slab)                                                         \
    {                                                                           \
        const ushort_t* bw = bbase + (size_t)(slab) * SLAB_E;                   \
        _Pragma("unroll") for (int ni = 0; ni < 2; ++ni)                        \
            _Pragma("unroll") for (int kb = 0; kb < 4; ++kb)                    \
                bf[ni][kb] = *(const short8*)(bw + (ni * 4 + kb) * 512);        \
    }
#define CONSUME(bf, s)                                                          \
    {                                                                           \
        _Pragma("unroll") for (int mi = 0; mi < 4; ++mi) {                      \
            ushort4 hv = *(const ushort4*)&HeT[s][rbase + mi * 16 + quad * 4];  \
            float h0 = b2f(hv.x), h1 = b2f(hv.y), h2 = b2f(hv.z), h3 = b2f(hv.w);\
            _Pragma("unroll") for (int ni = 0; ni < 2; ++ni) {                  \
                f32x4 p = {0.f, 0.f, 0.f, 0.f};                                 \
                _Pragma("unroll") for (int kb = 0; kb < 4; ++kb)                \
                    p = __builtin_amdgcn_mfma_f32_16x16x32_bf16(                \
                        afrag[mi][kb], bf[ni][kb], p, 0, 0, 0);                 \
                acc[mi][ni][0] = fmaf(h0, p[0], acc[mi][ni][0]);                \
                acc[mi][ni][1] = fmaf(h1, p[1], acc[mi][ni][1]);                \
                acc[mi][ni][2] = fmaf(h2, p[2], acc[mi][ni][2]);                \
                acc[mi][ni][3] = fmaf(h3, p[3], acc[mi][ni][3]);                \
            }                                                                   \
        }                                                                       \
    }

    short8 bfA[2][4], bfB[2][4];
    LOADB(bfA, k0);                       // prime slab 0
    for (int s = 0; s < KT_PER; s += 2) {
        LOADB(bfB, k0 + s + 1);           // prefetch odd slab (s+1 <= KT_PER-1)
        CONSUME(bfA, s);
        __builtin_amdgcn_s_barrier();     // phase-lock mg waves (L1/MSHR dedup)
        if (s + 2 < KT_PER) LOADB(bfA, k0 + s + 2)
        else if (ks == KSPLIT - 1) LOADB(bfA, HD);  // prefetch bias slab on last iter
        CONSUME(bfB, s + 1);
        __builtin_amdgcn_s_barrier();
    }
    if (ks == KSPLIT - 1) {   // bias slab kt=HD: h == 1.0 for every edge
#pragma unroll
        for (int mi = 0; mi < 4; ++mi)
#pragma unroll
            for (int ni = 0; ni < 2; ++ni) {
                f32x4 p = {0.f, 0.f, 0.f, 0.f};
#pragma unroll
                for (int kb = 0; kb < 4; ++kb)
                    p = __builtin_amdgcn_mfma_f32_16x16x32_bf16(
                        afrag[mi][kb], bfA[ni][kb], p, 0, 0, 0);
                acc[mi][ni][0] += p[0]; acc[mi][ni][1] += p[1];
                acc[mi][ni][2] += p[2]; acc[mi][ni][3] += p[3];
            }
    }
#undef LOADB
#undef CONSUME

    // scatter epilogue: row e = rbase + mi*16 + quad*4 + r, col = ng*32 + ni*16 + l16
#pragma unroll
    for (int mi = 0; mi < 4; ++mi) {
#pragma unroll
        for (int r = 0; r < 4; ++r) {
            const int dn = dst[e0 + rbase + mi * 16 + quad * 4 + r];
#pragma unroll
            for (int ni = 0; ni < 2; ++ni)
                atomicAdd(&agg[dn * HD + ng * 32 + ni * 16 + l16], acc[mi][ni][r]);
        }
    }
}

// ---- node update layers 2/3 (IN PLACE): act 1 = elu, 2 = leaky_relu ----
__global__ __launch_bounds__(128) void node_update(
    float* __restrict__ agg, const float* __restrict__ cnt,
    const float* __restrict__ hprev, const float* __restrict__ root, const float* __restrict__ bias,
    const float* __restrict__ lng, const float* __restrict__ lnb, int act) {
    const int n = blockIdx.x, o = threadIdx.x;
    __shared__ float hr[HD];
    hr[o] = hprev[n * HD + o];
    __syncthreads();
    float s = bias[o];
#pragma unroll 8
    for (int k = 0; k < HD; ++k) s = fmaf(hr[k], root[k * HD + o], s);
    float v = agg[n * HD + o] / fmaxf(cnt[n], 1.0f) + s;
    __shared__ float red[2];
    float ws = wave_sum(v);
    if ((o & 63) == 0) red[o >> 6] = ws;
    __syncthreads();
    float m = (red[0] + red[1]) * (1.0f / HD);
    float d = v - m;
    float ws2 = wave_sum(d * d);
    __syncthreads();
    if ((o & 63) == 0) red[o >> 6] = ws2;
    __syncthreads();
    float var = (red[0] + red[1]) * (1.0f / HD);
    float y = d * rsqrtf(var + 1e-5f) * lng[o] + lnb[o];
    if (act == 1) y = (y > 0.0f) ? y : expm1f(y);
    else y = (y > 0.0f) ? y : 0.01f * y;
    agg[n * HD + o] = y;
}

// ---- pooling phase 1: run-length reduce over SORTED batch --------------
static __device__ __forceinline__ unsigned fkey(float f) {
    unsigned b = __float_as_uint(f);
    return (b & 0x80000000u) ? ~b : (b | 0x80000000u);
}
__global__ __launch_bounds__(128) void pool_scatter(
    const float* __restrict__ h3, const int* __restrict__ batch,
    float* __restrict__ gsum, unsigned* __restrict__ gmaxk, int* __restrict__ gcnt) {
    const int o = threadIdx.x;            // 128 cols
    const int nb = blockIdx.x * PN;       // node base
    float sum = 0.0f, mx = -3.0e38f;
    int gcur = batch[nb];
    int run = 0;
    for (int j = 0; j < PN; ++j) {
        const int n = nb + j;
        const int g = batch[n];           // uniform across threads (sorted)
        const float v = h3[n * HD + o];
        if (g != gcur) {
            atomicAdd(&gsum[gcur * HD + o], sum);
            atomicMax(&gmaxk[gcur * HD + o], fkey(mx));
            if (o == 0) atomicAdd(&gcnt[gcur], run);
            sum = 0.0f; mx = -3.0e38f; run = 0; gcur = g;
        }
        sum += v; mx = fmaxf(mx, v); ++run;
    }
    atomicAdd(&gsum[gcur * HD + o], sum);
    atomicMax(&gmaxk[gcur * HD + o], fkey(mx));
    if (o == 0) atomicAdd(&gcnt[gcur], run);
}

// ---- pooling phase 2 + linear head; f32 out ----------------------------
__global__ __launch_bounds__(128) void pool_head2(
    const float* __restrict__ gsum, const unsigned* __restrict__ gmaxk, const int* __restrict__ gcnt,
    const float* __restrict__ cont, const float* __restrict__ ls,
    const float* __restrict__ lin_w, const float* __restrict__ lin_b, float* __restrict__ out) {
    const int g = blockIdx.x, o = threadIdx.x;
    const int c = gcnt[g];
    __shared__ float xcat[2 * HD + 5];
    xcat[o] = gsum[g * HD + o] / fmaxf((float)c, 1.0f);
    unsigned key = gmaxk[g * HD + o];
    unsigned bits = (key & 0x80000000u) ? (key & 0x7FFFFFFFu) : ~key;
    xcat[HD + o] = (c > 0) ? __uint_as_float(bits) : 0.0f;
    if (o < 4) xcat[2 * HD + o] = cont[g * 4 + o];
    if (o == 0) xcat[2 * HD + 4] = ls[g];
    __syncthreads();
    if (o < 2) {
        float r = lin_b[o];
        for (int ri = 0; ri < 2 * HD + 5; ++ri) r = fmaf(xcat[ri], lin_w[ri * 2 + o], r);
        out[g * 2 + o] = r;
    }
}

extern "C" void kernel_launch(void* const* d_in, const int* in_sizes, int n_in,
                              void* d_out, int out_size, void* d_ws, size_t ws_size,
                              hipStream_t stream) {
    const float* x     = (const float*)d_in[0];
    const int*   ei    = (const int*)d_in[1];
    const float* ea    = (const float*)d_in[2];
    const int*   batch = (const int*)d_in[3];
    const float* cont  = (const float*)d_in[4];
    const float* ls    = (const float*)d_in[5];
    const float *c1_w1 = (const float*)d_in[6],  *c1_b1 = (const float*)d_in[7];
    const float *c1_w2 = (const float*)d_in[8],  *c1_b2 = (const float*)d_in[9];
    const float *c1_rt = (const float*)d_in[10], *c1_bs = (const float*)d_in[11];
    const float *c2_w1 = (const float*)d_in[12], *c2_b1 = (const float*)d_in[13];
    const float *c2_w2 = (const float*)d_in[14], *c2_b2 = (const float*)d_in[15];
    const float *c2_rt = (const float*)d_in[16], *c2_bs = (const float*)d_in[17];
    const float *c3_w1 = (const float*)d_in[18], *c3_b1 = (const float*)d_in[19];
    const float *c3_w2 = (const float*)d_in[20], *c3_b2 = (const float*)d_in[21];
    const float *c3_rt = (const float*)d_in[22], *c3_bs = (const float*)d_in[23];
    const float *ln1g = (const float*)d_in[24], *ln1b = (const float*)d_in[25];
    const float *ln2g = (const float*)d_in[26], *ln2b = (const float*)d_in[27];
    const float *ln3g = (const float*)d_in[28], *ln3b = (const float*)d_in[29];
    const float *lin_w = (const float*)d_in[30], *lin_b = (const float*)d_in[31];
    float* out = (float*)d_out;

    // workspace: cnt 16KB | bufA 2MB | bufB 2MB | w2t 4.23MB | pool 16.5KB
    float*    cnt  = (float*)d_ws;
    float*    bufA = cnt + N_NODES;
    float*    bufB = bufA + N_NODES * HD;
    ushort_t* w2t  = (ushort_t*)(bufB + N_NODES * HD);
    float*    gsum = (float*)(w2t + (HD + 1) * HD * HD);
    unsigned* gmaxk = (unsigned*)(gsum + N_GRAPHS * HD);
    int*      gcnt = (int*)(gmaxk + N_GRAPHS * HD);
    const int* src = ei;
    const int* dst = ei + N_EDGES;

    hipMemsetAsync(cnt, 0, N_NODES * sizeof(float), stream);
    count_k<<<N_EDGES / 256, 256, 0, stream>>>(dst, cnt);

    // ---- layer 1 (VALU; small)
    hipMemsetAsync(bufA, 0, N_NODES * HD * sizeof(float), stream);
    l1_edge<<<N_EDGES / 4, 128, 0, stream>>>(x, src, dst, ea, c1_w1, c1_b1, c1_w2, c1_b2, bufA);
    node_update_l1<<<N_NODES, 128, 0, stream>>>(bufA, cnt, x, c1_rt, c1_bs, ln1g, ln1b);

    // ---- layer 2 (MFMA)
    w2t_prep<<<HD + 1, 256, 0, stream>>>(c2_w2, c2_b2, w2t);
    hipMemsetAsync(bufB, 0, N_NODES * HD * sizeof(float), stream);
    gemm_mfma<<<(N_EDGES / BM) * KSPLIT, 512, 0, stream>>>(bufA, ea, c2_w1, c2_b1, w2t, src, dst, bufB);
    node_update<<<N_NODES, 128, 0, stream>>>(bufB, cnt, bufA, c2_rt, c2_bs, ln2g, ln2b, 1);

    // ---- layer 3 (MFMA, reuses w2t buffer)
    w2t_prep<<<HD + 1, 256, 0, stream>>>(c3_w2, c3_b2, w2t);
    hipMemsetAsync(bufA, 0, N_NODES * HD * sizeof(float), stream);
    gemm_mfma<<<(N_EDGES / BM) * KSPLIT, 512, 0, stream>>>(bufB, ea, c3_w1, c3_b1, w2t, src, dst, bufA);
    node_update<<<N_NODES, 128, 0, stream>>>(bufA, cnt, bufB, c3_rt, c3_bs, ln3g, ln3b, 2);

    // ---- pool (run-length reduce over sorted batch) + head
    hipMemsetAsync(gsum, 0, (2 * N_GRAPHS * HD + N_GRAPHS) * sizeof(float), stream);
    pool_scatter<<<N_NODES / PN, 128, 0, stream>>>(bufA, batch, gsum, gmaxk, gcnt);
    pool_head2<<<N_GRAPHS, 128, 0, stream>>>(gsum, gmaxk, gcnt, cont, ls, lin_w, lin_b, out);
}

// Round 14
// 368.788 us; speedup vs baseline: 1.1043x; 1.1043x over previous
//
#include <hip/hip_runtime.h>
#include <hip/hip_bf16.h>

// Inputs f32 (proven R1/R4). Output f32.

#define N_NODES 4096
#define N_EDGES 16384
#define N_GRAPHS 16
#define HD 128   // hidden dim
#define BM 128   // edges per block in MFMA gemm
#define LDB 136  // padded LDS row stride in prep kernels only
#define KSPLIT 2              // k-slab splits, XCD-aligned (ks = bid&1)
#define KT_PER (HD / KSPLIT)  // 64 slabs per split
#define SLAB_E (HD * HD)      // ushorts per B slab (32 KB)
#define PN 32                 // nodes per pool_scatter block

typedef unsigned short ushort_t;
typedef __attribute__((ext_vector_type(8))) short short8;  // 8 bf16 = 4 VGPR (MFMA A/B frag)
typedef __attribute__((ext_vector_type(4))) float f32x4;   // MFMA C/D frag

static __device__ __forceinline__ ushort_t f2b(float f) {
    __hip_bfloat16 h = __float2bfloat16(f);
    union { __hip_bfloat16 h; ushort_t u; } cv; cv.h = h; return cv.u;
}
static __device__ __forceinline__ float b2f(ushort_t u) {
    union { unsigned u; float f; } cv; cv.u = ((unsigned)u) << 16; return cv.f;
}

static __device__ __forceinline__ float wave_sum(float v) {
#pragma unroll
    for (int off = 1; off < 64; off <<= 1) v += __shfl_xor(v, off, 64);
    return v;
}

// ---- per-node: edge count + scatter-sum of source features (for b2 term)
__global__ __launch_bounds__(256) void count_feat(
    const int* __restrict__ src, const int* __restrict__ dst, const float* __restrict__ x,
    float* __restrict__ cnt, float* __restrict__ sfeat) {
    int e = blockIdx.x * 256 + threadIdx.x;
    int d = dst[e], s = src[e];
    atomicAdd(&cnt[d], 1.0f);
    atomicAdd(&sfeat[d * 4 + 0], x[s * 3 + 0]);
    atomicAdd(&sfeat[d * 4 + 1], x[s * 3 + 1]);
    atomicAdd(&sfeat[d * 4 + 2], x[s * 3 + 2]);
}

// ---- layer-1 w2 fragment pack: 3 slabs, slab i: B[k][o] = w2[k][i*128+o]
__global__ __launch_bounds__(256) void w2r_prep(const float* __restrict__ w2,
                                                ushort_t* __restrict__ w2r) {
    __shared__ ushort_t tile[HD][LDB];
    const int i = blockIdx.x;   // 0..2
    const int t = threadIdx.x;
    for (int c = 0; c < 64; ++c) {
        int flat = c * 256 + t;          // coalesced over o
        int k = flat >> 7, o = flat & 127;
        tile[o][k] = f2b(w2[k * 384 + i * HD + o]);
    }
    __syncthreads();
    uint4* outp = (uint4*)(w2r + (size_t)i * SLAB_E);
    for (int it = 0; it < 8; ++it) {
        int c = it * 256 + t;            // output chunk, coalesced write
        int ng = c >> 9, j = (c >> 6) & 7, l = c & 63;
        int ni = j >> 2, kb = j & 3;
        int R  = ng * 32 + ni * 16 + (l & 15);
        int ke = kb * 32 + (l >> 4) * 8;
        outp[c] = *(const uint4*)&tile[R][ke];
    }
}

// ---- layer 1 as MFMA GEMM: msg[e,o] = sum_i x[src e,i] * (h[e] @ w2slab_i)[o]
// Same structure as gemm_mfma; per-slab row scalars are x_i instead of HeT.
__global__ __launch_bounds__(512, 2) void l1_gemm(
    const float* __restrict__ x, const int* __restrict__ src, const int* __restrict__ dst,
    const float* __restrict__ ea, const float* __restrict__ w1, const float* __restrict__ b1,
    const ushort_t* __restrict__ w2r, float* __restrict__ agg) {
    __shared__ ushort_t Hs[SLAB_E];   // 32 KB edge-MLP h (swizzled rows [e][k])
    __shared__ float    XV[3][BM];    // source features [i][e]

    const int t = threadIdx.x;
    const int lane = t & 63, quad = lane >> 4, l16 = lane & 15;
    const int wave = t >> 6;
    const int mg = wave >> 2;                 // 0..1 (64 edges each)
    const int ng = wave & 3;                  // 0..3 (32 cols each)
    const int e0 = blockIdx.x * BM;
    const int rbase = mg * 64;

    {   // build h (bf16, swizzled) + XV
        const int e = t & 127;
        const int kb32 = (t >> 7) * 32;       // this thread's 32-k range
        const float4 av = ((const float4*)ea)[e0 + e];
        if (t < 128) {
            const int n = src[e0 + t];
            XV[0][t] = x[n * 3 + 0]; XV[1][t] = x[n * 3 + 1]; XV[2][t] = x[n * 3 + 2];
        }
        const int r7 = e & 7;
        ushort_t* hrow = Hs + e * HD;
#pragma unroll
        for (int c = 0; c < 4; ++c) {
            const int kbase = kb32 + c * 8;
            unsigned pk0, pk1, pk2, pk3;
#pragma unroll
            for (int u = 0; u < 4; ++u) {
                const int ka = kbase + 2 * u, kb = ka + 1;
                float s0 = b1[ka];
                s0 = fmaf(av.x, w1[0 * HD + ka], s0);
                s0 = fmaf(av.y, w1[1 * HD + ka], s0);
                s0 = fmaf(av.z, w1[2 * HD + ka], s0);
                s0 = fmaf(av.w, w1[3 * HD + ka], s0);
                float s1 = b1[kb];
                s1 = fmaf(av.x, w1[0 * HD + kb], s1);
                s1 = fmaf(av.y, w1[1 * HD + kb], s1);
                s1 = fmaf(av.z, w1[2 * HD + kb], s1);
                s1 = fmaf(av.w, w1[3 * HD + kb], s1);
                unsigned pr = (unsigned)f2b(fmaxf(s0, 0.0f)) |
                              ((unsigned)f2b(fmaxf(s1, 0.0f)) << 16);
                if (u == 0) pk0 = pr; else if (u == 1) pk1 = pr;
                else if (u == 2) pk2 = pr; else pk3 = pr;
            }
            uint4 v; v.x = pk0; v.y = pk1; v.z = pk2; v.w = pk3;
            *(uint4*)&hrow[(((kbase >> 3) ^ r7) << 3)] = v;
        }
    }
    __syncthreads();

    short8 afrag[4][4];  // h[e = rbase+mi*16+l16][k = kb*32+quad*8+j]
#pragma unroll
    for (int mi = 0; mi < 4; ++mi) {
        const int R = rbase + mi * 16 + l16;
        const ushort_t* rowp = Hs + R * HD;
        const int r7 = R & 7;
#pragma unroll
        for (int kb = 0; kb < 4; ++kb)
            afrag[mi][kb] = *(const short8*)&rowp[((kb * 4 + quad) ^ r7) << 3];
    }

    f32x4 acc[4][2];
#pragma unroll
    for (int mi = 0; mi < 4; ++mi)
#pragma unroll
        for (int ni = 0; ni < 2; ++ni)
            acc[mi][ni] = (f32x4){0.f, 0.f, 0.f, 0.f};

    const ushort_t* bbase = w2r + (size_t)ng * 4096 + (size_t)lane * 8;

#define LOADB(bf, slab)                                                         \
    {                                                                           \
        const ushort_t* bw = bbase + (size_t)(slab) * SLAB_E;                   \
        _Pragma("unroll") for (int ni = 0; ni < 2; ++ni)                        \
            _Pragma("unroll") for (int kb = 0; kb < 4; ++kb)                    \
                bf[ni][kb] = *(const short8*)(bw + (ni * 4 + kb) * 512);        \
    }
#define CONSUME_XV(bf, i)                                                       \
    {                                                                           \
        _Pragma("unroll") for (int mi = 0; mi < 4; ++mi) {                      \
            float4 xv = *(const float4*)&XV[i][rbase + mi * 16 + quad * 4];     \
            _Pragma("unroll") for (int ni = 0; ni < 2; ++ni) {                  \
                f32x4 p = {0.f, 0.f, 0.f, 0.f};                                 \
                _Pragma("unroll") for (int kb = 0; kb < 4; ++kb)                \
                    p = __builtin_amdgcn_mfma_f32_16x16x32_bf16(                \
                        afrag[mi][kb], bf[ni][kb], p, 0, 0, 0);                 \
                acc[mi][ni][0] = fmaf(xv.x, p[0], acc[mi][ni][0]);              \
                acc[mi][ni][1] = fmaf(xv.y, p[1], acc[mi][ni][1]);              \
                acc[mi][ni][2] = fmaf(xv.z, p[2], acc[mi][ni][2]);              \
                acc[mi][ni][3] = fmaf(xv.w, p[3], acc[mi][ni][3]);              \
            }                                                                   \
        }                                                                       \
    }

    short8 bfA[2][4], bfB[2][4];
    LOADB(bfA, 0);
    LOADB(bfB, 1);
    CONSUME_XV(bfA, 0);
    LOADB(bfA, 2);
    CONSUME_XV(bfB, 1);
    CONSUME_XV(bfA, 2);
#undef LOADB
#undef CONSUME_XV

#pragma unroll
    for (int mi = 0; mi < 4; ++mi) {
#pragma unroll
        for (int r = 0; r < 4; ++r) {
            const int dn = dst[e0 + rbase + mi * 16 + quad * 4 + r];
#pragma unroll
            for (int ni = 0; ni < 2; ++ni)
                atomicAdd(&agg[dn * HD + ng * 32 + ni * 16 + l16], acc[mi][ni][r]);
        }
    }
}

// ---- layer-1 node update: agg := relu(LN((agg + S@b2r)/cnt + x@root + b))
__global__ __launch_bounds__(128) void node_update_l1(
    float* __restrict__ agg, const float* __restrict__ cnt, const float* __restrict__ sfeat,
    const float* __restrict__ x, const float* __restrict__ root, const float* __restrict__ bias,
    const float* __restrict__ b2, const float* __restrict__ lng, const float* __restrict__ lnb) {
    const int n = blockIdx.x, o = threadIdx.x;
    float s = bias[o];
#pragma unroll
    for (int i = 0; i < 3; ++i) s = fmaf(x[n * 3 + i], root[i * HD + o], s);
    float sb = 0.0f;
#pragma unroll
    for (int i = 0; i < 3; ++i) sb = fmaf(sfeat[n * 4 + i], b2[i * HD + o], sb);
    float v = (agg[n * HD + o] + sb) / fmaxf(cnt[n], 1.0f) + s;
    __shared__ float red[2];
    float ws = wave_sum(v);
    if ((o & 63) == 0) red[o >> 6] = ws;
    __syncthreads();
    float m = (red[0] + red[1]) * (1.0f / HD);
    float d = v - m;
    float ws2 = wave_sum(d * d);
    __syncthreads();
    if ((o & 63) == 0) red[o >> 6] = ws2;
    __syncthreads();
    float var = (red[0] + red[1]) * (1.0f / HD);
    float y = d * rsqrtf(var + 1e-5f) * lng[o] + lnb[o];
    agg[n * HD + o] = fmaxf(y, 0.0f);
}

// ---- one-time transpose+convert+FRAGMENT-ORDER pack (layers 2/3) -------
__global__ __launch_bounds__(256) void w2t_prep(const float* __restrict__ w2,
                                                const float* __restrict__ b2,
                                                ushort_t* __restrict__ w2t) {
    __shared__ ushort_t tile[HD][LDB];
    const int kt = blockIdx.x;  // 0..128
    const int t = threadIdx.x;
    const float* srcp = (kt < HD) ? (w2 + kt * HD * HD) : b2;
    for (int c = 0; c < 64; ++c) {
        int flat = c * 256 + t;          // coalesced over o
        int i = flat >> 7, o = flat & 127;
        tile[o][i] = f2b(srcp[i * HD + o]);
    }
    __syncthreads();
    uint4* outp = (uint4*)(w2t + (size_t)kt * SLAB_E);
    for (int it = 0; it < 8; ++it) {
        int c = it * 256 + t;
        int ng = c >> 9, j = (c >> 6) & 7, l = c & 63;
        int ni = j >> 2, kb = j & 3;
        int R  = ng * 32 + ni * 16 + (l & 15);
        int ke = kb * 32 + (l >> 4) * 8;
        outp[c] = *(const uint4*)&tile[R][ke];
    }
}

// ---- heavy layers 2/3: MFMA GEMM, B straight from L1/L2 (R12, proven) --
__global__ __launch_bounds__(512, 2) void gemm_mfma(
    const float* __restrict__ hprev, const float* __restrict__ ea,
    const float* __restrict__ w1, const float* __restrict__ b1,
    const ushort_t* __restrict__ w2t,
    const int* __restrict__ src, const int* __restrict__ dst,
    float* __restrict__ agg) {
    __shared__ ushort_t Xs[SLAB_E];           // 32 KB gathered A (swizzled)
    __shared__ ushort_t HeT[KT_PER][BM];      // 16 KB edge-MLP outputs [s][e]

    const int t = threadIdx.x;
    const int lane = t & 63, quad = lane >> 4, l16 = lane & 15;
    const int wave = t >> 6;
    const int mg = wave >> 2;                 // M-group 0..1 (64 edges each)
    const int ng = wave & 3;                  // N-group 0..3 (32 cols each)
    const int eb = blockIdx.x >> 1;           // edge group 0..127
    const int ks = blockIdx.x & 1;            // k-split, XCD-aligned
    const int k0 = ks * KT_PER;
    const int e0 = eb * BM;
    const int rbase = mg * 64;                // wave's edge-row base

    {   // stage gathered A (bf16, XOR-swizzled chunks) into Xs
        const int le = t >> 2;                // edge 0..127, 4 threads/edge
        const int j0 = (t & 3) * 4;           // first logical 16B chunk
        const int r7 = le & 7;
        const float* rp = hprev + src[e0 + le] * HD + (t & 3) * 32;
        ushort_t* xrow = Xs + le * HD;
#pragma unroll
        for (int c = 0; c < 4; ++c) {
            float4 va = ((const float4*)rp)[2 * c];
            float4 vb = ((const float4*)rp)[2 * c + 1];
            uint4 pk;
            pk.x = (unsigned)f2b(va.x) | ((unsigned)f2b(va.y) << 16);
            pk.y = (unsigned)f2b(va.z) | ((unsigned)f2b(va.w) << 16);
            pk.z = (unsigned)f2b(vb.x) | ((unsigned)f2b(vb.y) << 16);
            pk.w = (unsigned)f2b(vb.z) | ((unsigned)f2b(vb.w) << 16);
            *(uint4*)&xrow[((j0 + c) ^ r7) << 3] = pk;
        }
    }

    {   // edge MLP -> HeT[s][e] (bf16); attrs straight from global
        const int e = t & 127;
        const float4 av = ((const float4*)ea)[e0 + e];
        for (int kl = t >> 7; kl < KT_PER; kl += 4) {
            const int kt = k0 + kl;
            float s = b1[kt];
            s = fmaf(av.x, w1[0 * HD + kt], s);
            s = fmaf(av.y, w1[1 * HD + kt], s);
            s = fmaf(av.z, w1[2 * HD + kt], s);
            s = fmaf(av.w, w1[3 * HD + kt], s);
            HeT[kl][e] = f2b(fmaxf(s, 0.0f));
        }
    }
    __syncthreads();   // Xs + HeT visible; the only full barrier

    short8 afrag[4][4];  // A[m = rbase+mi*16+l16][k = kb*32+quad*8+j]
#pragma unroll
    for (int mi = 0; mi < 4; ++mi) {
        const int R = rbase + mi * 16 + l16;
        const ushort_t* rowp = Xs + R * HD;
        const int r7 = R & 7;
#pragma unroll
        for (int kb = 0; kb < 4; ++kb)
            afrag[mi][kb] = *(const short8*)&rowp[((kb * 4 + quad) ^ r7) << 3];
    }

    f32x4 acc[4][2];
#pragma unroll
    for (int mi = 0; mi < 4; ++mi)
#pragma unroll
        for (int ni = 0; ni < 2; ++ni)
            acc[mi][ni] = (f32x4){0.f, 0.f, 0.f, 0.f};

    const ushort_t* bbase = w2t + (size_t)ng * 4096 + (size_t)lane * 8;

#define LOADB(bf, slab)                                                         \
    {                                                                           \
        const ushort_t* bw = bbase + (size_t)(slab) * SLAB_E;                   \
        _Pragma("unroll") for (int ni = 0; ni < 2; ++ni)                        \
            _Pragma("unroll") for (int kb = 0; kb < 4; ++kb)                    \
                bf[ni][kb] = *(const short8*)(bw + (ni * 4 + kb) * 512);        \
    }
#define CONSUME(bf, s)                                                          \
    {                                                                           \
        _Pragma("unroll") for (int mi = 0; mi < 4; ++mi) {                      \
            ushort4 hv = *(const ushort4*)&HeT[s][rbase + mi * 16 + quad * 4];  \
            float h0 = b2f(hv.x), h1 = b2f(hv.y), h2 = b2f(hv.z), h3 = b2f(hv.w);\
            _Pragma("unroll") for (int ni = 0; ni < 2; ++ni) {                  \
                f32x4 p = {0.f, 0.f, 0.f, 0.f};                                 \
                _Pragma("unroll") for (int kb = 0; kb < 4; ++kb)                \
                    p = __builtin_amdgcn_mfma_f32_16x16x32_bf16(                \
                        afrag[mi][kb], bf[ni][kb], p, 0, 0, 0);                 \
                acc[mi][ni][0] = fmaf(h0, p[0], acc[mi][ni][0]);                \
                acc[mi][ni][1] = fmaf(h1, p[1], acc[mi][ni][1]);                \
                acc[mi][ni][2] = fmaf(h2, p[2], acc[mi][ni][2]);                \
                acc[mi][ni][3] = fmaf(h3, p[3], acc[mi][ni][3]);                \
            }                                                                   \
        }                                                                       \
    }

    short8 bfA[2][4], bfB[2][4];
    LOADB(bfA, k0);                       // prime slab 0
    for (int s = 0; s < KT_PER; s += 2) {
        LOADB(bfB, k0 + s + 1);           // prefetch odd slab
        CONSUME(bfA, s);
        __builtin_amdgcn_s_barrier();     // phase-lock mg waves (L1/MSHR dedup)
        if (s + 2 < KT_PER) LOADB(bfA, k0 + s + 2)
        else if (ks == 1)   LOADB(bfA, HD);   // prefetch bias slab on last iter
        CONSUME(bfB, s + 1);
        __builtin_amdgcn_s_barrier();
    }
    if (ks == 1) {   // bias slab kt=HD: h == 1.0 for every edge
#pragma unroll
        for (int mi = 0; mi < 4; ++mi)
#pragma unroll
            for (int ni = 0; ni < 2; ++ni) {
                f32x4 p = {0.f, 0.f, 0.f, 0.f};
#pragma unroll
                for (int kb = 0; kb < 4; ++kb)
                    p = __builtin_amdgcn_mfma_f32_16x16x32_bf16(
                        afrag[mi][kb], bfA[ni][kb], p, 0, 0, 0);
                acc[mi][ni][0] += p[0]; acc[mi][ni][1] += p[1];
                acc[mi][ni][2] += p[2]; acc[mi][ni][3] += p[3];
            }
    }
#undef LOADB
#undef CONSUME

    // scatter epilogue: row e = rbase + mi*16 + quad*4 + r, col = ng*32 + ni*16 + l16
#pragma unroll
    for (int mi = 0; mi < 4; ++mi) {
#pragma unroll
        for (int r = 0; r < 4; ++r) {
            const int dn = dst[e0 + rbase + mi * 16 + quad * 4 + r];
#pragma unroll
            for (int ni = 0; ni < 2; ++ni)
                atomicAdd(&agg[dn * HD + ng * 32 + ni * 16 + l16], acc[mi][ni][r]);
        }
    }
}

// ---- node update layers 2/3 (IN PLACE): act 1 = elu, 2 = leaky_relu ----
__global__ __launch_bounds__(128) void node_update(
    float* __restrict__ agg, const float* __restrict__ cnt,
    const float* __restrict__ hprev, const float* __restrict__ root, const float* __restrict__ bias,
    const float* __restrict__ lng, const float* __restrict__ lnb, int act) {
    const int n = blockIdx.x, o = threadIdx.x;
    __shared__ float hr[HD];
    hr[o] = hprev[n * HD + o];
    __syncthreads();
    float s = bias[o];
#pragma unroll 8
    for (int k = 0; k < HD; ++k) s = fmaf(hr[k], root[k * HD + o], s);
    float v = agg[n * HD + o] / fmaxf(cnt[n], 1.0f) + s;
    __shared__ float red[2];
    float ws = wave_sum(v);
    if ((o & 63) == 0) red[o >> 6] = ws;
    __syncthreads();
    float m = (red[0] + red[1]) * (1.0f / HD);
    float d = v - m;
    float ws2 = wave_sum(d * d);
    __syncthreads();
    if ((o & 63) == 0) red[o >> 6] = ws2;
    __syncthreads();
    float var = (red[0] + red[1]) * (1.0f / HD);
    float y = d * rsqrtf(var + 1e-5f) * lng[o] + lnb[o];
    if (act == 1) y = (y > 0.0f) ? y : expm1f(y);
    else y = (y > 0.0f) ? y : 0.01f * y;
    agg[n * HD + o] = y;
}

// ---- pooling phase 1: run-length reduce over SORTED batch --------------
static __device__ __forceinline__ unsigned fkey(float f) {
    unsigned b = __float_as_uint(f);
    return (b & 0x80000000u) ? ~b : (b | 0x80000000u);
}
__global__ __launch_bounds__(128) void pool_scatter(
    const float* __restrict__ h3, const int* __restrict__ batch,
    float* __restrict__ gsum, unsigned* __restrict__ gmaxk, int* __restrict__ gcnt) {
    const int o = threadIdx.x;            // 128 cols
    const int nb = blockIdx.x * PN;       // node base
    float sum = 0.0f, mx = -3.0e38f;
    int gcur = batch[nb];
    int run = 0;
    for (int j = 0; j < PN; ++j) {
        const int n = nb + j;
        const int g = batch[n];           // uniform across threads (sorted)
        const float v = h3[n * HD + o];
        if (g != gcur) {
            atomicAdd(&gsum[gcur * HD + o], sum);
            atomicMax(&gmaxk[gcur * HD + o], fkey(mx));
            if (o == 0) atomicAdd(&gcnt[gcur], run);
            sum = 0.0f; mx = -3.0e38f; run = 0; gcur = g;
        }
        sum += v; mx = fmaxf(mx, v); ++run;
    }
    atomicAdd(&gsum[gcur * HD + o], sum);
    atomicMax(&gmaxk[gcur * HD + o], fkey(mx));
    if (o == 0) atomicAdd(&gcnt[gcur], run);
}

// ---- pooling phase 2 + linear head; f32 out ----------------------------
__global__ __launch_bounds__(128) void pool_head2(
    const float* __restrict__ gsum, const unsigned* __restrict__ gmaxk, const int* __restrict__ gcnt,
    const float* __restrict__ cont, const float* __restrict__ ls,
    const float* __restrict__ lin_w, const float* __restrict__ lin_b, float* __restrict__ out) {
    const int g = blockIdx.x, o = threadIdx.x;
    const int c = gcnt[g];
    __shared__ float xcat[2 * HD + 5];
    xcat[o] = gsum[g * HD + o] / fmaxf((float)c, 1.0f);
    unsigned key = gmaxk[g * HD + o];
    unsigned bits = (key & 0x80000000u) ? (key & 0x7FFFFFFFu) : ~key;
    xcat[HD + o] = (c > 0) ? __uint_as_float(bits) : 0.0f;
    if (o < 4) xcat[2 * HD + o] = cont[g * 4 + o];
    if (o == 0) xcat[2 * HD + 4] = ls[g];
    __syncthreads();
    if (o < 2) {
        float r = lin_b[o];
        for (int ri = 0; ri < 2 * HD + 5; ++ri) r = fmaf(xcat[ri], lin_w[ri * 2 + o], r);
        out[g * 2 + o] = r;
    }
}

extern "C" void kernel_launch(void* const* d_in, const int* in_sizes, int n_in,
                              void* d_out, int out_size, void* d_ws, size_t ws_size,
                              hipStream_t stream) {
    const float* x     = (const float*)d_in[0];
    const int*   ei    = (const int*)d_in[1];
    const float* ea    = (const float*)d_in[2];
    const int*   batch = (const int*)d_in[3];
    const float* cont  = (const float*)d_in[4];
    const float* ls    = (const float*)d_in[5];
    const float *c1_w1 = (const float*)d_in[6],  *c1_b1 = (const float*)d_in[7];
    const float *c1_w2 = (const float*)d_in[8],  *c1_b2 = (const float*)d_in[9];
    const float *c1_rt = (const float*)d_in[10], *c1_bs = (const float*)d_in[11];
    const float *c2_w1 = (const float*)d_in[12], *c2_b1 = (const float*)d_in[13];
    const float *c2_w2 = (const float*)d_in[14], *c2_b2 = (const float*)d_in[15];
    const float *c2_rt = (const float*)d_in[16], *c2_bs = (const float*)d_in[17];
    const float *c3_w1 = (const float*)d_in[18], *c3_b1 = (const float*)d_in[19];
    const float *c3_w2 = (const float*)d_in[20], *c3_b2 = (const float*)d_in[21];
    const float *c3_rt = (const float*)d_in[22], *c3_bs = (const float*)d_in[23];
    const float *ln1g = (const float*)d_in[24], *ln1b = (const float*)d_in[25];
    const float *ln2g = (const float*)d_in[26], *ln2b = (const float*)d_in[27];
    const float *ln3g = (const float*)d_in[28], *ln3b = (const float*)d_in[29];
    const float *lin_w = (const float*)d_in[30], *lin_b = (const float*)d_in[31];
    float* out = (float*)d_out;

    // workspace: cnt 16KB | sfeat 64KB | bufA 2MB | bufB 2MB | w2t 4.23MB | pool
    float*    cnt   = (float*)d_ws;
    float*    sfeat = cnt + N_NODES;
    float*    bufA  = sfeat + 4 * N_NODES;
    float*    bufB  = bufA + N_NODES * HD;
    ushort_t* w2t   = (ushort_t*)(bufB + N_NODES * HD);   // also reused as w2r (l1)
    float*    gsum  = (float*)(w2t + (HD + 1) * HD * HD);
    unsigned* gmaxk = (unsigned*)(gsum + N_GRAPHS * HD);
    int*      gcnt  = (int*)(gmaxk + N_GRAPHS * HD);
    const int* src = ei;
    const int* dst = ei + N_EDGES;

    hipMemsetAsync(cnt, 0, 5 * N_NODES * sizeof(float), stream);   // cnt + sfeat
    count_feat<<<N_EDGES / 256, 256, 0, stream>>>(src, dst, x, cnt, sfeat);

    // ---- layer 1 (MFMA GEMM over G = x (x) h, K = 384)
    w2r_prep<<<3, 256, 0, stream>>>(c1_w2, w2t);
    hipMemsetAsync(bufA, 0, N_NODES * HD * sizeof(float), stream);
    l1_gemm<<<N_EDGES / BM, 512, 0, stream>>>(x, src, dst, ea, c1_w1, c1_b1, w2t, bufA);
    node_update_l1<<<N_NODES, 128, 0, stream>>>(bufA, cnt, sfeat, x, c1_rt, c1_bs, c1_b2, ln1g, ln1b);

    // ---- layer 2 (MFMA)
    w2t_prep<<<HD + 1, 256, 0, stream>>>(c2_w2, c2_b2, w2t);
    hipMemsetAsync(bufB, 0, N_NODES * HD * sizeof(float), stream);
    gemm_mfma<<<(N_EDGES / BM) * KSPLIT, 512, 0, stream>>>(bufA, ea, c2_w1, c2_b1, w2t, src, dst, bufB);
    node_update<<<N_NODES, 128, 0, stream>>>(bufB, cnt, bufA, c2_rt, c2_bs, ln2g, ln2b, 1);

    // ---- layer 3 (MFMA, reuses w2t buffer)
    w2t_prep<<<HD + 1, 256, 0, stream>>>(c3_w2, c3_b2, w2t);
    hipMemsetAsync(bufA, 0, N_NODES * HD * sizeof(float), stream);
    gemm_mfma<<<(N_EDGES / BM) * KSPLIT, 512, 0, stream>>>(bufB, ea, c3_w1, c3_b1, w2t, src, dst, bufA);
    node_update<<<N_NODES, 128, 0, stream>>>(bufA, cnt, bufB, c3_rt, c3_bs, ln3g, ln3b, 2);

    // ---- pool (run-length reduce over sorted batch) + head
    hipMemsetAsync(gsum, 0, (2 * N_GRAPHS * HD + N_GRAPHS) * sizeof(float), stream);
    pool_scatter<<<N_NODES / PN, 128, 0, stream>>>(bufA, batch, gsum, gmaxk, gcnt);
    pool_head2<<<N_GRAPHS, 128, 0, stream>>>(gsum, gmaxk, gcnt, cont, ls, lin_w, lin_b, out);
}